// Round 5
// baseline (50.835 us; speedup 1.0000x reference)
//
#include <hip/hip_runtime.h>
#include <math.h>

// Problem constants: V=50000, D=100, B=16, S=128, U=100, L=2
#define NB 16
#define SS 128
#define DD 100
#define KK 100
#define T_TILE 8
#define NTILES 16
#define NT 512            // 8 waves
#define ROWF 112          // floats per scratch row (448B: whole 64B lines)
#define VSTR 52           // LDS floats per (part,k) row
#define VPLANE 5200       // 100 * VSTR
#define XROW(b,t) ((((b) << 7) + (t)) * ROWF)

typedef float sf16 __attribute__((ext_vector_type(16)));
typedef float sf8  __attribute__((ext_vector_type(8)));
typedef float sf4  __attribute__((ext_vector_type(4)));

// Scalar loads: x-vectors are wave-uniform -> SGPRs; v_fma uses its 1-SGPR slot.
// SAFETY RULE: an address may be s_loaded only AFTER its final vector write in
// this dispatch (K$ is never invalidated mid-kernel; first touch must be late).
__device__ __forceinline__ sf16 sl16(const float* p) {
  sf16 r; asm volatile("s_load_dwordx16 %0, %1, 0x0" : "=s"(r) : "s"((unsigned long long)p)); return r;
}
__device__ __forceinline__ sf8 sl8(const float* p) {
  sf8 r; asm volatile("s_load_dwordx8 %0, %1, 0x0" : "=s"(r) : "s"((unsigned long long)p)); return r;
}
__device__ __forceinline__ sf4 sl4(const float* p) {
  sf4 r; asm volatile("s_load_dwordx4 %0, %1, 0x0" : "=s"(r) : "s"((unsigned long long)p)); return r;
}

// ---------------------------------------------------------------------------
// Global V-chunk -> registers -> LDS ([part][k][d4local], stride VSTR)
// ---------------------------------------------------------------------------
template<int NF4>
__device__ __forceinline__ void vload(const float* __restrict__ sr, const float* __restrict__ si,
                                      int cd, int tid, float4 (&vr)[6]) {
  const int tot = 2 * KK * NF4;
#pragma unroll
  for (int i = 0; i < 6; ++i) {
    const int e = tid + i * NT;
    if (e < tot) {
      const int part = e / (KK * NF4);
      const int r = e - part * (KK * NF4);
      const int k = r / NF4;
      const int j = r - k * NF4;
      vr[i] = *(const float4*)((part ? si : sr) + k * DD + cd + 4 * j);
    }
  }
}
template<int NF4>
__device__ __forceinline__ void vstore(float* __restrict__ vbuf, int tid, const float4 (&vr)[6]) {
  const int tot = 2 * KK * NF4;
#pragma unroll
  for (int i = 0; i < 6; ++i) {
    const int e = tid + i * NT;
    if (e < tot) {
      const int part = e / (KK * NF4);
      const int r = e - part * (KK * NF4);
      const int k = r / NF4;
      const int j = r - k * NF4;
      *(float4*)&vbuf[part * VPLANE + k * VSTR + 4 * j] = vr[i];
    }
  }
}

#define NRM() nacc += vr.x*vr.x+vr.y*vr.y+vr.z*vr.z+vr.w*vr.w \
                    + vi.x*vi.x+vi.y*vi.y+vi.z*vi.z+vi.w*vi.w
#define C0B(AX, BX, P) \
  ar[P]+=vr.x*AX[4*u+0]+vr.y*AX[4*u+1]+vr.z*AX[4*u+2]+vr.w*AX[4*u+3] \
       +vi.x*BX[4*u+0]+vi.y*BX[4*u+1]+vi.z*BX[4*u+2]+vi.w*BX[4*u+3]; \
  ai[P]+=vr.x*BX[4*u+0]+vr.y*BX[4*u+1]+vr.z*BX[4*u+2]+vr.w*BX[4*u+3] \
       -vi.x*AX[4*u+0]-vi.y*AX[4*u+1]-vi.z*AX[4*u+2]-vi.w*AX[4*u+3];
#define C1B(AX, P) \
  ar[P]+=vr.x*AX[4*u+0]+vr.y*AX[4*u+1]+vr.z*AX[4*u+2]+vr.w*AX[4*u+3]; \
  ai[P]+=vi.x*AX[4*u+0]+vi.y*AX[4*u+1]+vi.z*AX[4*u+2]+vi.w*AX[4*u+3];

// Complex-x chunk (stage 1): subs of 2 d4, dwordx8 per part per position
template<int ND4>
__device__ __forceinline__ void fma_c0(const float* __restrict__ vbuf, int ke,
    const float* xr0, const float* xr1, const float* xr2,
    const float* xi0, const float* xi1, const float* xi2,
    int cd, float (&ar)[3], float (&ai)[3], float& nacc) {
  const float* vb = vbuf + ke * VSTR;
#pragma unroll 1
  for (int s = 0; s < ND4 / 2; ++s) {
    sf8 a0 = sl8(xr0 + cd + 8*s), a1 = sl8(xr1 + cd + 8*s), a2 = sl8(xr2 + cd + 8*s);
    sf8 b0 = sl8(xi0 + cd + 8*s), b1 = sl8(xi1 + cd + 8*s), b2 = sl8(xi2 + cd + 8*s);
    asm volatile("s_waitcnt lgkmcnt(0)"
                 : "+s"(a0), "+s"(a1), "+s"(a2), "+s"(b0), "+s"(b1), "+s"(b2));
#pragma unroll
    for (int u = 0; u < 2; ++u) {
      const float4 vr = *(const float4*)(vb + (2*s+u)*4);
      const float4 vi = *(const float4*)(vb + VPLANE + (2*s+u)*4);
      NRM();
      C0B(a0, b0, 0) C0B(a1, b1, 1) C0B(a2, b2, 2)
    }
  }
  if (ND4 & 1) {
    const int off = cd + 8 * (ND4 / 2);
    sf4 a0 = sl4(xr0 + off), a1 = sl4(xr1 + off), a2 = sl4(xr2 + off);
    sf4 b0 = sl4(xi0 + off), b1 = sl4(xi1 + off), b2 = sl4(xi2 + off);
    asm volatile("s_waitcnt lgkmcnt(0)"
                 : "+s"(a0), "+s"(a1), "+s"(a2), "+s"(b0), "+s"(b1), "+s"(b2));
    const int u = 0;
    const float4 vr = *(const float4*)(vb + (ND4-1)*4);
    const float4 vi = *(const float4*)(vb + VPLANE + (ND4-1)*4);
    NRM();
    C0B(a0, b0, 0) C0B(a1, b1, 1) C0B(a2, b2, 2)
  }
}

// Real-x chunk (stages 2,3): subs of 4 d4, dwordx16 per position
template<int ND4>
__device__ __forceinline__ void fma_c1(const float* __restrict__ vbuf, int ke,
    const float* x0, const float* x1, const float* x2,
    int cd, float (&ar)[3], float (&ai)[3], float& nacc) {
  const float* vb = vbuf + ke * VSTR;
#pragma unroll 1
  for (int s = 0; s < ND4 / 4; ++s) {
    sf16 a0 = sl16(x0 + cd + 16*s), a1 = sl16(x1 + cd + 16*s), a2 = sl16(x2 + cd + 16*s);
    asm volatile("s_waitcnt lgkmcnt(0)" : "+s"(a0), "+s"(a1), "+s"(a2));
#pragma unroll
    for (int u = 0; u < 4; ++u) {
      const float4 vr = *(const float4*)(vb + (4*s+u)*4);
      const float4 vi = *(const float4*)(vb + VPLANE + (4*s+u)*4);
      NRM();
      C1B(a0, 0) C1B(a1, 1) C1B(a2, 2)
    }
  }
  if (ND4 & 3) {
    const int off = cd + 16 * (ND4 / 4);
    sf4 a0 = sl4(x0 + off), a1 = sl4(x1 + off), a2 = sl4(x2 + off);
    asm volatile("s_waitcnt lgkmcnt(0)" : "+s"(a0), "+s"(a1), "+s"(a2));
    const int u = 0;
    const float4 vr = *(const float4*)(vb + (ND4-1)*4);
    const float4 vi = *(const float4*)(vb + VPLANE + (ND4-1)*4);
    NRM();
    C1B(a0, 0) C1B(a1, 1) C1B(a2, 2)
  }
}

// One projection stage: V chunk-staged to LDS (chunk 1 prefetched during
// chunk-0 FMA), x via s_load from global scratch, row norms in-loop.
template<int MODE>
__device__ __forceinline__ void run_stage(
    const float* __restrict__ gvr, const float* __restrict__ gvi,
    const float* xr0, const float* xr1, const float* xr2,
    const float* xi0, const float* xi1, const float* xi2,
    float* __restrict__ vbuf, float* __restrict__ invvn,
    int tid, int ke, bool nwrite, float (&ar)[3], float (&ai)[3]) {
  float4 vreg[6];
  ar[0] = ar[1] = ar[2] = 0.f; ai[0] = ai[1] = ai[2] = 0.f;
  float nacc = 0.f;
  vload<12>(gvr, gvi, 0, tid, vreg);
  vstore<12>(vbuf, tid, vreg);
  __syncthreads();
  vload<13>(gvr, gvi, 48, tid, vreg);   // prefetch chunk 1 during chunk-0 FMA
  if (MODE == 0) fma_c0<12>(vbuf, ke, xr0, xr1, xr2, xi0, xi1, xi2, 0, ar, ai, nacc);
  else           fma_c1<12>(vbuf, ke, xr0, xr1, xr2, 0, ar, ai, nacc);
  __syncthreads();
  vstore<13>(vbuf, tid, vreg);
  __syncthreads();
  if (MODE == 0) fma_c0<13>(vbuf, ke, xr0, xr1, xr2, xi0, xi1, xi2, 48, ar, ai, nacc);
  else           fma_c1<13>(vbuf, ke, xr0, xr1, xr2, 48, ar, ai, nacc);
  __syncthreads();
  if (nwrite) invvn[ke] = 1.0f / nacc;
  __syncthreads();
}

// ---------------------------------------------------------------------------
__global__ __launch_bounds__(NT) void k_fused(
    const int* __restrict__ seq,
    const float* __restrict__ ampT, const float* __restrict__ phT,
    const float* __restrict__ pkr, const float* __restrict__ pki,
    const float* __restrict__ mkr, const float* __restrict__ mki,
    float* __restrict__ PR, float* __restrict__ PI,
    float* __restrict__ M1, float* __restrict__ M2,
    float* __restrict__ part) {
  __shared__ float vbuf[2 * VPLANE];     // 41.6 KB
  __shared__ float2 y2l[11 * 102];       // 9 KB
  __shared__ float es[SS], wnl[SS], invvn[KK];
  __shared__ float redw[2], sc[3];

  const int tid  = threadIdx.x;
  const int lane = tid & 63;
  const int wid  = __builtin_amdgcn_readfirstlane(tid >> 6);
  const int bt   = blockIdx.x;
  const int b    = bt >> 4;
  const int t0   = (bt & 15) * T_TILE;
  const int sb   = b * SS;
  const int q    = wid & 1;
  const int pg   = wid >> 1;
  const int ke   = q * 50 + (lane < 50 ? lane : 49);
  const int pp0 = pg, pp1 = pg + 4, pp2 = pg + 8;

  // --- prologue A: ||amp|| and exp for all 128 positions of batch b ---
  {
    const int t = tid >> 2, qq = tid & 3;
    const int row = seq[sb + t];
    const float* ap = ampT + (long)row * DD + qq;
    float s = 0.f;
#pragma unroll
    for (int i = 0; i < 25; ++i) { const float a = ap[4*i]; s += a * a; }
    s += __shfl_xor(s, 1); s += __shfl_xor(s, 2);
    if (qq == 0) { const float n = sqrtf(s); wnl[t] = n; es[t] = expf(n); }
  }
  __syncthreads();
  {
    float v = (tid < SS) ? es[tid] : 0.f;
    if (tid < SS) {
      for (int m = 32; m; m >>= 1) v += __shfl_xor(v, m);
      if (lane == 0) redw[tid >> 6] = v;
    }
  }
  // --- prologue B: phi = (amp/||amp||) e^{i phase} -> PR/PI rows (halo) ---
  for (int e = tid; e < 11 * DD; e += NT) {
    const int p = e / DD, d = e - p * DD;
    const int t = t0 + p;
    if (t < SS) {
      const int row = seq[sb + t];
      const float a  = ampT[(long)row * DD + d];
      const float ph = phT[(long)row * DD + d];
      float sv, cv; sincosf(ph, &sv, &cv);
      const float an = a / wnl[t];
      PR[XROW(b, t) + d] = an * cv;
      PI[XROW(b, t) + d] = an * sv;
    }
  }
  __syncthreads();
  if (tid == 0) {
    const float E = redw[0] + redw[1];
    sc[0] = E; sc[1] = E - es[0] + 1.0f; sc[2] = E - es[0] - es[1] + 2.0f;
  }
  __syncthreads();

  float ar[3], ai[3];
  const bool nwr = (wid < 2) && (lane < 63 ? (lane < 50) : false);

  // --- stage 1 (complex x = phi; x rows clamped into OWN written halo) ---
  {
    const int r0 = min(t0 + min(pp0, 10), SS - 1);
    const int r1 = min(t0 + min(pp1, 10), SS - 1);
    const int r2 = min(t0 + min(pp2, 10), SS - 1);
    run_stage<0>(pkr, pki,
                 PR + XROW(b, r0), PR + XROW(b, r1), PR + XROW(b, r2),
                 PI + XROW(b, r0), PI + XROW(b, r1), PI + XROW(b, r2),
                 vbuf, invvn, tid, ke, nwr, ar, ai);
#pragma unroll
    for (int j = 0; j < 3; ++j) {
      const int pp = pg + 4 * j;
      const int t = t0 + pp;
      if (pp < 11 && t < SS && lane < 50)
        M1[XROW(b, t) + ke] = (ar[j] * ar[j] + ai[j] * ai[j]) * invvn[ke];
    }
    __syncthreads();   // vmcnt drained -> M1 visible in L2 before first s_load
  }

  // --- stage 2 (real x = m1) ---
  {
    const int r0 = min(t0 + min(pp0, 10), SS - 1);
    const int r1 = min(t0 + min(pp1, 10), SS - 1);
    const int r2 = min(t0 + min(pp2, 10), SS - 1);
    run_stage<1>(pkr + DD * DD, pki + DD * DD,
                 M1 + XROW(b, r0), M1 + XROW(b, r1), M1 + XROW(b, r2),
                 nullptr, nullptr, nullptr,
                 vbuf, invvn, tid, ke, nwr, ar, ai);
#pragma unroll
    for (int j = 0; j < 3; ++j) {
      const int pp = pg + 4 * j;
      if (pp < 11 && lane < 50) y2l[pp * 102 + ke] = make_float2(ar[j], ai[j]);
    }
    __syncthreads();
    // 2-tap window mix -> m2 (GRID-STRIDE loop: 1000 elements, 512 threads!)
    for (int idx = tid; idx < 10 * KK; idx += NT) {
      const int p = idx / KK, k = idx - p * KK;
      const int t = t0 + p;
      if (t < SS) {
        const float w0 = es[t] / sc[0];
        float qr = w0 * y2l[p * 102 + k].x;
        float qi = w0 * y2l[p * 102 + k].y;
        if (t + 1 < SS) {
          const float w1 = es[t + 1] / sc[1];
          qr += w1 * y2l[(p + 1) * 102 + k].x;
          qi += w1 * y2l[(p + 1) * 102 + k].y;
        }
        M2[XROW(b, t) + k] = (qr * qr + qi * qi) * invvn[k];
      }
    }
    __syncthreads();   // M2 visible
  }

  // --- stage 3 (real x = m2, measurement) ---
  {
    const int r0 = min(t0 + min(pp0, 9), SS - 1);
    const int r1 = min(t0 + min(pp1, 9), SS - 1);
    const int r2 = min(t0 + min(pp2, 9), SS - 1);
    run_stage<1>(mkr, mki,
                 M2 + XROW(b, r0), M2 + XROW(b, r1), M2 + XROW(b, r2),
                 nullptr, nullptr, nullptr,
                 vbuf, invvn, tid, ke, nwr, ar, ai);
#pragma unroll
    for (int j = 0; j < 3; ++j) {
      const int pp = pg + 4 * j;
      if (pp < 10 && lane < 50) y2l[pp * 102 + ke] = make_float2(ar[j], ai[j]);
    }
    __syncthreads();
    // 3-tap window, |.|^2, * wn[t] * invvn; sum over the tile's 8 positions
    if (tid < KK) {
      const int k = tid;
      float accf = 0.f;
#pragma unroll
      for (int p = 0; p < T_TILE; ++p) {
        const int t = t0 + p;
        const float w0 = es[t] / sc[0];
        float qr = w0 * y2l[p * 102 + k].x;
        float qi = w0 * y2l[p * 102 + k].y;
        if (t + 1 < SS) {
          const float w1 = es[t + 1] / sc[1];
          qr += w1 * y2l[(p + 1) * 102 + k].x;
          qi += w1 * y2l[(p + 1) * 102 + k].y;
        }
        if (t + 2 < SS) {
          const float w2 = es[t + 2] / sc[2];
          qr += w2 * y2l[(p + 2) * 102 + k].x;
          qi += w2 * y2l[(p + 2) * 102 + k].y;
        }
        accf += wnl[t] * (qr * qr + qi * qi);
      }
      part[bt * KK + k] = accf * invvn[k];
    }
  }
}

// ---------------------------------------------------------------------------
__global__ __launch_bounds__(128) void k_out(
    const float* __restrict__ part, const float* __restrict__ dw,
    const float* __restrict__ db, float* __restrict__ out) {
  __shared__ float pr[KK];
  const int b = blockIdx.x, tid = threadIdx.x;
  if (tid < KK) {
    float s = 0.f;
#pragma unroll
    for (int qq = 0; qq < NTILES; ++qq) s += part[(b * NTILES + qq) * KK + tid];
    pr[tid] = s;
  }
  __syncthreads();
  if (tid < 2) {
    float s = db[tid];
    for (int k = 0; k < KK; ++k) s += pr[k] * dw[k * 2 + tid];
    out[b * 2 + tid] = s;
  }
}

// ---------------------------------------------------------------------------
extern "C" void kernel_launch(void* const* d_in, const int* in_sizes, int n_in,
                              void* d_out, int out_size, void* d_ws, size_t ws_size,
                              hipStream_t stream) {
  const int*   seq  = (const int*)d_in[0];
  const float* ampT = (const float*)d_in[1];
  const float* phT  = (const float*)d_in[2];
  const float* pkr  = (const float*)d_in[3];
  const float* pki  = (const float*)d_in[4];
  const float* mkr  = (const float*)d_in[5];
  const float* mki  = (const float*)d_in[6];
  const float* dw   = (const float*)d_in[7];
  const float* db   = (const float*)d_in[8];
  float* out = (float*)d_out;

  float* ws = (float*)d_ws;
  const int R = NB * SS * ROWF;              // 229376 floats per buffer
  // DISTINCT buffers per intermediate: no global address is ever s_loaded
  // before its final vector write (scalar cache is not invalidated mid-kernel).
  float* PR   = ws;                          // phi real
  float* PI   = ws + R;                      // phi imag
  float* M1   = ws + 2 * R;                  // stage-1 output
  float* M2   = ws + 3 * R;                  // stage-2 output
  float* part = ws + 4 * R;                  // [256][100]
  // total ws use: 4*R + 25600 floats = ~3.69 MB

  k_fused<<<NB * NTILES, NT, 0, stream>>>(seq, ampT, phT, pkr, pki, mkr, mki,
                                          PR, PI, M1, M2, part);
  k_out  <<<NB,          128, 0, stream>>>(part, dw, db, out);
}

// Round 6
// 37.853 us; speedup vs baseline: 1.3430x; 1.3430x over previous
//
#include <hip/hip_runtime.h>
#include <math.h>

// Problem constants: V=50000, D=100, B=16, S=128, U=100, L=2
#define NB 16
#define SS 128
#define DD 100
#define KK 100
#define T_TILE 8
#define NTILES 16
#define NT 768          // 12 waves = 4 d-quarters x 3 pos-groups, 3 waves/SIMD

__device__ __forceinline__ float dot4(const float4 a, const float4 b) {
  return a.x * b.x + a.y * b.y + a.z * b.z + a.w * b.w;
}

// ---------------------------------------------------------------------------
// One projection stage.
//   MODE 0: complex x (phi);  MODE 1: real x.
//   CM 1: m_next = |Y|^2*inv            (stage 1)
//   CM 2: m_next = |w0*Y(p)+w1*Y(p+1)|^2*inv   (stage 2, 2-tap window)
//   CM 3: y3 = Y raw (+ invvnU)          (stage 3; 3-tap window done in final)
// Each lane owns k-pair (k0,k0+1); wave covers d-quarter df4 (f4 units),
// positions 4g+e. V streamed global->VGPR in two halves (NA,NB2 f4 rows);
// x broadcast from LDS. Partials combined via partl[4][11][50] (deterministic).
// ---------------------------------------------------------------------------
template<int MODE, int CM, int NA, int NB2>
__device__ __forceinline__ void do_stage(
    const float* __restrict__ gvr, const float* __restrict__ gvi,
    const float4 (*__restrict__ xR)[25], const float4 (*__restrict__ xI)[25],
    float4 (*__restrict__ partl)[11][50],
    float2 (*__restrict__ nrmh)[50],
    float* __restrict__ mdst, float2* __restrict__ y3f,
    float* __restrict__ invvnU,
    const float* __restrict__ es, const float* __restrict__ sc,
    int df4, int pmaxF, int pmaxC,
    int k0, bool act, int g, int h, int t0)
{
  const float* vr0 = gvr + k0 * DD + 4 * df4;
  const float* vi0 = gvi + k0 * DD + 4 * df4;
  float acr[4][2] = {{0.f,0.f},{0.f,0.f},{0.f,0.f},{0.f,0.f}};
  float aci[4][2] = {{0.f,0.f},{0.f,0.f},{0.f,0.f},{0.f,0.f}};
  float n0 = 0.f, n1 = 0.f;

  // ---- half A ----
  {
    float4 V[NA][2][2];
#pragma unroll
    for (int j = 0; j < NA; ++j) {
      V[j][0][0] = *(const float4*)(vr0 + 4 * j);
      V[j][1][0] = *(const float4*)(vr0 + DD + 4 * j);
      V[j][0][1] = *(const float4*)(vi0 + 4 * j);
      V[j][1][1] = *(const float4*)(vi0 + DD + 4 * j);
    }
#pragma unroll
    for (int j = 0; j < NA; ++j) {
      n0 += dot4(V[j][0][0], V[j][0][0]) + dot4(V[j][0][1], V[j][0][1]);
      n1 += dot4(V[j][1][0], V[j][1][0]) + dot4(V[j][1][1], V[j][1][1]);
    }
#pragma unroll
    for (int e = 0; e < 4; ++e) {
      const int p = 4 * g + e;
      if (p <= pmaxF) {
        const float4* xrow  = &xR[p][df4];
        const float4* xirow = &xI[p][df4];
#pragma unroll
        for (int j = 0; j < NA; ++j) {
          const float4 xr = xrow[j];
          if (MODE == 0) {
            const float4 xi = xirow[j];
            acr[e][0] += dot4(V[j][0][0], xr) + dot4(V[j][0][1], xi);
            aci[e][0] += dot4(V[j][0][0], xi) - dot4(V[j][0][1], xr);
            acr[e][1] += dot4(V[j][1][0], xr) + dot4(V[j][1][1], xi);
            aci[e][1] += dot4(V[j][1][0], xi) - dot4(V[j][1][1], xr);
          } else {
            acr[e][0] += dot4(V[j][0][0], xr);
            aci[e][0] += dot4(V[j][0][1], xr);
            acr[e][1] += dot4(V[j][1][0], xr);
            aci[e][1] += dot4(V[j][1][1], xr);
          }
        }
      }
    }
  }
  // ---- half B ----
  {
    float4 V[NB2][2][2];
#pragma unroll
    for (int j = 0; j < NB2; ++j) {
      V[j][0][0] = *(const float4*)(vr0 + 4 * (NA + j));
      V[j][1][0] = *(const float4*)(vr0 + DD + 4 * (NA + j));
      V[j][0][1] = *(const float4*)(vi0 + 4 * (NA + j));
      V[j][1][1] = *(const float4*)(vi0 + DD + 4 * (NA + j));
    }
#pragma unroll
    for (int j = 0; j < NB2; ++j) {
      n0 += dot4(V[j][0][0], V[j][0][0]) + dot4(V[j][0][1], V[j][0][1]);
      n1 += dot4(V[j][1][0], V[j][1][0]) + dot4(V[j][1][1], V[j][1][1]);
    }
#pragma unroll
    for (int e = 0; e < 4; ++e) {
      const int p = 4 * g + e;
      if (p <= pmaxF) {
        const float4* xrow  = &xR[p][df4 + NA];
        const float4* xirow = &xI[p][df4 + NA];
#pragma unroll
        for (int j = 0; j < NB2; ++j) {
          const float4 xr = xrow[j];
          if (MODE == 0) {
            const float4 xi = xirow[j];
            acr[e][0] += dot4(V[j][0][0], xr) + dot4(V[j][0][1], xi);
            aci[e][0] += dot4(V[j][0][0], xi) - dot4(V[j][0][1], xr);
            acr[e][1] += dot4(V[j][1][0], xr) + dot4(V[j][1][1], xi);
            aci[e][1] += dot4(V[j][1][0], xi) - dot4(V[j][1][1], xr);
          } else {
            acr[e][0] += dot4(V[j][0][0], xr);
            aci[e][0] += dot4(V[j][0][1], xr);
            acr[e][1] += dot4(V[j][1][0], xr);
            aci[e][1] += dot4(V[j][1][1], xr);
          }
        }
      }
    }
  }

  const int kp = k0 >> 1;
  if (act) {
#pragma unroll
    for (int e = 0; e < 4; ++e) {
      const int p = 4 * g + e;
      if (p <= pmaxF)
        partl[h][p][kp] = make_float4(acr[e][0], aci[e][0], acr[e][1], aci[e][1]);
    }
    if (g == 0) nrmh[h][kp] = make_float2(n0, n1);
  }
  __syncthreads();

  // ---- combine (h==0 waves only) ----
  if (h == 0 && act) {
    const float2 q0 = nrmh[0][kp], q1 = nrmh[1][kp], q2 = nrmh[2][kp], q3 = nrmh[3][kp];
    const float iv0 = 1.f / (q0.x + q1.x + q2.x + q3.x);
    const float iv1 = 1.f / (q0.y + q1.y + q2.y + q3.y);
#pragma unroll
    for (int e = 0; e < 4; ++e) {
      const int p = 4 * g + e;
      if (p <= pmaxC) {
        float4 s  = partl[0][p][kp];
        float4 b1 = partl[1][p][kp], b2 = partl[2][p][kp], b3 = partl[3][p][kp];
        s.x += b1.x + b2.x + b3.x;  s.y += b1.y + b2.y + b3.y;
        s.z += b1.z + b2.z + b3.z;  s.w += b1.w + b2.w + b3.w;
        if (CM == 1) {
          *(float2*)(mdst + p * 100 + k0) =
              make_float2((s.x * s.x + s.y * s.y) * iv0,
                          (s.z * s.z + s.w * s.w) * iv1);
        } else if (CM == 2) {
          float4 u  = partl[0][p + 1][kp];
          float4 c1 = partl[1][p + 1][kp], c2 = partl[2][p + 1][kp], c3 = partl[3][p + 1][kp];
          u.x += c1.x + c2.x + c3.x;  u.y += c1.y + c2.y + c3.y;
          u.z += c1.z + c2.z + c3.z;  u.w += c1.w + c2.w + c3.w;
          const int t = t0 + p;
          const float w0 = es[t] / sc[0];     // es zero-padded past SS
          const float w1 = es[t + 1] / sc[1];
          const float r0 = w0 * s.x + w1 * u.x, i0 = w0 * s.y + w1 * u.y;
          const float r1 = w0 * s.z + w1 * u.z, i1 = w0 * s.w + w1 * u.w;
          *(float2*)(mdst + p * 100 + k0) =
              make_float2((r0 * r0 + i0 * i0) * iv0, (r1 * r1 + i1 * i1) * iv1);
        } else {
          *(float4*)(y3f + p * 100 + k0) = s;   // (r0,i0,r1,i1)
        }
      }
    }
    if (CM == 3 && g == 0) { invvnU[k0] = iv0; invvnU[k0 + 1] = iv1; }
  }
  __syncthreads();
}

// ---------------------------------------------------------------------------
__global__ __launch_bounds__(NT, 3) void k_fused(
    const int* __restrict__ seq,
    const float* __restrict__ ampT, const float* __restrict__ phT,
    const float* __restrict__ pkr, const float* __restrict__ pki,
    const float* __restrict__ mkr, const float* __restrict__ mki,
    float* __restrict__ partg)
{
  __shared__ float4 xbR[11][25];          // phi_r, then m1 (4.4 KB)
  __shared__ float4 xbI[11][25];          // phi_i, then m2 (4.4 KB)
  __shared__ float4 partl[4][11][50];     // per-d-quarter partials (35.2 KB)
  __shared__ float2 y3[10][100];          // stage-3 Y (8 KB)
  __shared__ float2 nrmh[4][50];          // row-norm partials (1.6 KB)
  __shared__ float invvnU[KK];
  __shared__ float es[SS + 8];            // zero-padded tail
  __shared__ float wnl[SS];
  __shared__ float redw[2];
  __shared__ float sc[3];

  const int tid  = threadIdx.x;
  const int lane = tid & 63;
  const int wid  = tid >> 6;      // 0..11
  const int h    = wid & 3;       // d-quarter
  const int g    = wid >> 2;      // position-group (0..2)
  const bool act = lane < 50;
  const int kp   = act ? lane : 49;
  const int k0   = 2 * kp;
  const int df4  = (h == 0) ? 0 : 7 + 6 * (h - 1);   // f4 offset of quarter
  const int bt   = blockIdx.x;
  const int b    = bt >> 4;
  const int t0   = (bt & 15) * T_TILE;
  const int sb   = b * SS;

  // --- prologue A: ||amp|| + exp for all 128 positions of batch b ---
  if (tid < 512) {
    const int t = tid >> 2, qq = tid & 3;
    const int row = seq[sb + t];
    const float* ap = ampT + (long)row * DD;
    float s = 0.f;
#pragma unroll
    for (int i = 0; i < 7; ++i) {
      const int j = qq + 4 * i;
      if (j < 25) {
        const float4 a = *(const float4*)(ap + 4 * j);
        s += a.x * a.x + a.y * a.y + a.z * a.z + a.w * a.w;
      }
    }
    s += __shfl_xor(s, 1);
    s += __shfl_xor(s, 2);
    if (qq == 0) { const float n = sqrtf(s); wnl[t] = n; es[t] = expf(n); }
  }
  if (tid >= 512 && tid < 520) es[SS + tid - 512] = 0.f;  // zero pad
  __syncthreads();

  // --- prologue B: E + closed-form softmax denominators ---
  if (tid < SS) {
    float v = es[tid];
#pragma unroll
    for (int m = 32; m; m >>= 1) v += __shfl_xor(v, m);
    if ((tid & 63) == 0) redw[tid >> 6] = v;
  }
  // --- prologue C: phi = (amp/||amp||) e^{i phase} -> LDS (zero past seq end) ---
  for (int e2 = tid; e2 < 11 * DD; e2 += NT) {
    const int p = e2 / DD, d = e2 - p * DD;
    const int t = t0 + p;
    float pr = 0.f, pi = 0.f;
    if (t < SS) {
      const int row = seq[sb + t];
      const float a  = ampT[(long)row * DD + d];
      const float ph = phT[(long)row * DD + d];
      float sv, cv; sincosf(ph, &sv, &cv);
      const float an = a / wnl[t];
      pr = an * cv; pi = an * sv;
    }
    ((float*)xbR)[p * 100 + d] = pr;
    ((float*)xbI)[p * 100 + d] = pi;
  }
  __syncthreads();
  if (tid == 0) {
    const float E = redw[0] + redw[1];
    sc[0] = E; sc[1] = E - es[0] + 1.f; sc[2] = E - es[0] - es[1] + 2.f;
  }
  __syncthreads();

  // --- stage 1: m1[p,k] = |<v0_k, phi_p>|^2 / ||v0_k||^2   (p<=10) ---
  if (h == 0) do_stage<0,1,4,3>(pkr, pki, xbR, xbI, partl, nrmh,
                                (float*)xbR, nullptr, invvnU, es, sc,
                                0,   10, 10, k0, act, g, h, t0);
  else        do_stage<0,1,3,3>(pkr, pki, xbR, xbI, partl, nrmh,
                                (float*)xbR, nullptr, invvnU, es, sc,
                                df4, 10, 10, k0, act, g, h, t0);

  // --- stage 2: Y2 = <v1_k, m1_p>; m2[p] = |w0 Y2(p)+w1 Y2(p+1)|^2*iv (p<=9) ---
  if (h == 0) do_stage<1,2,4,3>(pkr + DD * DD, pki + DD * DD, xbR, xbI, partl, nrmh,
                                (float*)xbI, nullptr, invvnU, es, sc,
                                0,   10, 9, k0, act, g, h, t0);
  else        do_stage<1,2,3,3>(pkr + DD * DD, pki + DD * DD, xbR, xbI, partl, nrmh,
                                (float*)xbI, nullptr, invvnU, es, sc,
                                df4, 10, 9, k0, act, g, h, t0);

  // --- stage 3: y3[p] = <u_k, m2_p> raw (p<=9), + measurement row norms ---
  if (h == 0) do_stage<1,3,4,3>(mkr, mki, xbI, xbI, partl, nrmh,
                                nullptr, (float2*)y3, invvnU, es, sc,
                                0,   9, 9, k0, act, g, h, t0);
  else        do_stage<1,3,3,3>(mkr, mki, xbI, xbI, partl, nrmh,
                                nullptr, (float2*)y3, invvnU, es, sc,
                                df4, 9, 9, k0, act, g, h, t0);

  // --- final: 3-tap window on Y3, square, * wn[t], * invvnU; sum over tile ---
  if (tid < KK) {
    const int k = tid;
    const float iE = 1.f / sc[0], iZ1 = 1.f / sc[1], iZ2 = 1.f / sc[2];
    float acc = 0.f;
#pragma unroll
    for (int p = 0; p < T_TILE; ++p) {
      const int t = t0 + p;
      const float w0 = es[t] * iE;
      const float w1 = es[t + 1] * iZ1;   // es zero-padded -> terms vanish
      const float w2 = es[t + 2] * iZ2;
      const float2 a = y3[p][k], bb = y3[p + 1][k], c = y3[p + 2][k];
      const float qr = w0 * a.x + w1 * bb.x + w2 * c.x;
      const float qi = w0 * a.y + w1 * bb.y + w2 * c.y;
      acc += wnl[t] * (qr * qr + qi * qi);
    }
    partg[bt * KK + k] = acc * invvnU[k];
  }
}

// ---------------------------------------------------------------------------
__global__ __launch_bounds__(128) void k_out(
    const float* __restrict__ partg, const float* __restrict__ dw,
    const float* __restrict__ db, float* __restrict__ out)
{
  __shared__ float pr[KK];
  const int b = blockIdx.x, tid = threadIdx.x;
  if (tid < KK) {
    float s = 0.f;
#pragma unroll
    for (int q = 0; q < NTILES; ++q) s += partg[(b * NTILES + q) * KK + tid];
    pr[tid] = s;
  }
  __syncthreads();
  if (tid < 2) {
    float s = db[tid];
    for (int k = 0; k < KK; ++k) s += pr[k] * dw[k * 2 + tid];
    out[b * 2 + tid] = s;
  }
}

// ---------------------------------------------------------------------------
extern "C" void kernel_launch(void* const* d_in, const int* in_sizes, int n_in,
                              void* d_out, int out_size, void* d_ws, size_t ws_size,
                              hipStream_t stream) {
  const int*   seq  = (const int*)d_in[0];
  const float* ampT = (const float*)d_in[1];
  const float* phT  = (const float*)d_in[2];
  const float* pkr  = (const float*)d_in[3];
  const float* pki  = (const float*)d_in[4];
  const float* mkr  = (const float*)d_in[5];
  const float* mki  = (const float*)d_in[6];
  const float* dw   = (const float*)d_in[7];
  const float* db   = (const float*)d_in[8];
  float* out   = (float*)d_out;
  float* partg = (float*)d_ws;    // 256*100 floats = 102.4 KB, only global scratch

  k_fused<<<NB * NTILES, NT, 0, stream>>>(seq, ampT, phT, pkr, pki, mkr, mki, partg);
  k_out  <<<NB,          128, 0, stream>>>(partg, dw, db, out);
}